// Round 8
// baseline (365.397 us; speedup 1.0000x reference)
//
#include <hip/hip_runtime.h>

#define TSEQ 256
#define FIN  32
#define HID  64

#define LOG2E    1.4426950408889634f
#define TWOLOG2E 2.8853900817779268f

typedef _Float16 f16x8 __attribute__((ext_vector_type(8)));
typedef __fp16   h16x2 __attribute__((ext_vector_type(2)));   // cvt_pkrtz return type
typedef float    f32x4 __attribute__((ext_vector_type(4)));

// Raw v_exp_f32 (flush-to-zero below 2^-126). FTZ is the mathematically
// correct limit for sigmoid/tanh decode. __builtin_exp2f lowers to OCML's
// IEEE exp2f with a subnormal fixup (~8 VALU/call) -- R8's regression.
#if __has_builtin(__builtin_amdgcn_exp2f)
__device__ __forceinline__ float fast_exp2(float x) { return __builtin_amdgcn_exp2f(x); }
#else
extern "C" __device__ float __ocml_native_exp2_f32(float);
__device__ __forceinline__ float fast_exp2(float x) { return __ocml_native_exp2_f32(x); }
#endif

// Barrier with LDS-only drain: __syncthreads() forces vmcnt(0) too, which
// couples the x global-load prefetch latency into every barrier. Only the
// ds_writes must be visible across the barrier (LDS is CU-local).
#define BAR_LDS() do { asm volatile("s_waitcnt lgkmcnt(0)" ::: "memory"); \
                       __builtin_amdgcn_s_barrier(); } while (0)

__device__ __forceinline__ float wsum(float v) {
    #pragma unroll
    for (int off = 32; off > 0; off >>= 1) v += __shfl_xor(v, off, 64);
    return v;
}

// Gates arrive PRE-SCALED by the weights/biases (log2e folded in):
//   g0 = -log2e*i, g1 = -log2e*f, g2 = 2log2e*g, g3 = -log2e*o
// Merged-denominator decode: one rcp serves sigma(f) AND sigma(i)*tanh(g).
// Trans ops/cell: 5 exp + 2 rcp. c clamped +-15 via med3.
__device__ __forceinline__ float lstm_cell(const f32x4 g, float& c) {
    float ei = fast_exp2(g[0]);
    float ef = fast_exp2(g[1]);
    float yg = fast_exp2(g[2]);
    float eo = fast_exp2(g[3]);
    float t1 = 1.0f + ei;
    float t2 = 1.0f + ef;
    float p  = t1 * (yg + 1.0f);
    float r  = __builtin_amdgcn_rcpf(p * t2);
    float ig = (yg - 1.0f) * t2 * r;   // sigma(i)*tanh(g)
    float sf = p * r;                  // sigma(f)
    c = fmaf(sf, c, ig);
    float cc = __builtin_amdgcn_fmed3f(c, -15.0f, 15.0f);
    float yc = fast_exp2(TWOLOG2E * cc);
    return (yc - 1.0f) * __builtin_amdgcn_rcpf((1.0f + eo) * (yc + 1.0f));
}

// R11 = R10 (layer-specialized waves, 2 gate-tiles/wave, x direct-from-
// global, fast_exp2 cell) + overlap package:
//  - BAR_LDS raw barrier (no vmcnt drain; x prefetch spans barriers)
//  - A-waves: register-only x-MFMAs issued BEFORE the LDS reads
//  - B-waves: split reads (H0 pair -> 4 MFMA -> H1 pair -> 4 MFMA)
//  - xcur built with v_cvt_pkrtz (4 instr vs 8 cvt + packs)
__global__ __launch_bounds__(1024, 4)
void lstm_fused(const float* __restrict__ x,
                const float* __restrict__ w_ih0, const float* __restrict__ w_hh0,
                const float* __restrict__ b_ih0, const float* __restrict__ b_hh0,
                const float* __restrict__ w_ih1, const float* __restrict__ w_hh1,
                const float* __restrict__ b_ih1, const float* __restrict__ b_hh1,
                const float* __restrict__ ln_g, const float* __restrict__ ln_b,
                const float* __restrict__ w1, const float* __restrict__ b1,
                const float* __restrict__ w2, const float* __restrict__ b2,
                float* __restrict__ out)
{
    __shared__ __align__(16) _Float16 H0[2][16][72];  // h0 parity buffers
    __shared__ __align__(16) _Float16 H1[2][16][72];  // h1 parity buffers
    __shared__ __align__(16) float HF[16][68];        // final h1 (fp32) for head
    __shared__ __align__(16) float LNB[16][64];       // per-wave layernorm row

    const int tid  = threadIdx.x;
    const int wave = tid >> 6;
    const int lane = tid & 63;
    const int q    = lane >> 4;
    const int lm   = lane & 15;
    const int q8   = q * 8;
    const int b0   = blockIdx.x * 16;

    const bool isA = wave < 8;
    const int  wt  = wave & 7;
    const int  T0  = 2 * wt, T1 = T0 + 1;
    // A-fragment rows (m = lm within tile), n' = 4d+type permutation
    const int  np0  = T0 * 16 + lm;
    const int  np1  = T1 * 16 + lm;
    const int  row0 = (np0 & 3) * 64 + (np0 >> 2);
    const int  row1 = (np1 & 3) * 64 + (np1 >> 2);
    // decoded d per lane for each tile (C layout: reg r = gate type r of d)
    const int  d0 = T0 * 4 + q;
    const int  d1 = T1 * 4 + q;
    // log2e folding: weight row's gate type = lm & 3 (g rows get +2log2e)
    const float wsc = ((lm & 3) == 2) ? TWOLOG2E : -LOG2E;

    // wf: A-waves use [0..5] = {x,h0a,h0b}x{tile0,tile1};
    //     B-waves use [0..7] = {ih_a,ih_b,hh_a,hh_b}x{tile0,tile1}
    f16x8 wf[8];
    f32x4 bias0, bias1;
    if (isA) {
        const float* p0 = w_ih0 + row0 * FIN + q8;
        const float* p1 = w_hh0 + row0 * HID + q8;
        const float* p2 = w_hh0 + row0 * HID + 32 + q8;
        const float* p3 = w_ih0 + row1 * FIN + q8;
        const float* p4 = w_hh0 + row1 * HID + q8;
        const float* p5 = w_hh0 + row1 * HID + 32 + q8;
        #pragma unroll
        for (int j = 0; j < 8; ++j) {
            wf[0][j] = (_Float16)(wsc * p0[j]);
            wf[1][j] = (_Float16)(wsc * p1[j]);
            wf[2][j] = (_Float16)(wsc * p2[j]);
            wf[3][j] = (_Float16)(wsc * p3[j]);
            wf[4][j] = (_Float16)(wsc * p4[j]);
            wf[5][j] = (_Float16)(wsc * p5[j]);
        }
        #pragma unroll
        for (int r = 0; r < 4; ++r) {
            const float s = (r == 2) ? TWOLOG2E : -LOG2E;
            bias0[r] = s * (b_ih0[r * 64 + d0] + b_hh0[r * 64 + d0]);
            bias1[r] = s * (b_ih0[r * 64 + d1] + b_hh0[r * 64 + d1]);
        }
    } else {
        const float* p0 = w_ih1 + row0 * HID + q8;
        const float* p1 = w_ih1 + row0 * HID + 32 + q8;
        const float* p2 = w_hh1 + row0 * HID + q8;
        const float* p3 = w_hh1 + row0 * HID + 32 + q8;
        const float* p4 = w_ih1 + row1 * HID + q8;
        const float* p5 = w_ih1 + row1 * HID + 32 + q8;
        const float* p6 = w_hh1 + row1 * HID + q8;
        const float* p7 = w_hh1 + row1 * HID + 32 + q8;
        #pragma unroll
        for (int j = 0; j < 8; ++j) {
            wf[0][j] = (_Float16)(wsc * p0[j]);
            wf[1][j] = (_Float16)(wsc * p1[j]);
            wf[2][j] = (_Float16)(wsc * p2[j]);
            wf[3][j] = (_Float16)(wsc * p3[j]);
            wf[4][j] = (_Float16)(wsc * p4[j]);
            wf[5][j] = (_Float16)(wsc * p5[j]);
            wf[6][j] = (_Float16)(wsc * p6[j]);
            wf[7][j] = (_Float16)(wsc * p7[j]);
        }
        #pragma unroll
        for (int r = 0; r < 4; ++r) {
            const float s = (r == 2) ? TWOLOG2E : -LOG2E;
            bias0[r] = s * (b_ih1[r * 64 + d0] + b_hh1[r * 64 + d0]);
            bias1[r] = s * (b_ih1[r * 64 + d1] + b_hh1[r * 64 + d1]);
        }
    }

    // x prefetch registers: xfa/xfb hold x(i) in f32 at interval-i entry
    const float* xp = x + (size_t)(b0 + lm) * TSEQ * FIN + q8;
    f32x4 xfa, xfb;
    if (isA) {
        xfa = *reinterpret_cast<const f32x4*>(xp);
        xfb = *reinterpret_cast<const f32x4*>(xp + 4);
    }

    // zero h state (both parities)
    for (int i = tid; i < 2 * 16 * 72; i += 1024) {
        ((_Float16*)H0)[i] = (_Float16)0.0f;
        ((_Float16*)H1)[i] = (_Float16)0.0f;
    }
    float c0a = 0.0f, c0b = 0.0f, c1a = 0.0f, c1b = 0.0f;
    float lastB0 = 0.0f, lastB1 = 0.0f;
    __syncthreads();

#define MFMA __builtin_amdgcn_mfma_f32_16x16x32_f16
// Interval i (parity P=i&1): A-waves compute h0(i) reading H0[P^1]=h0(i-1),
// writing H0[P]; B-waves compute h1(i-1) reading H0[P^1] and H1[P]=h1(i-2),
// writing H1[P^1]. x: convert prefetched x(i), issue load of x(XI=i+1).
#define INTERVAL(P, DO_A, DO_B, DO_XL, XI)                                          \
    {                                                                               \
        if (isA) {                                                                  \
            f16x8 xcur;                                                             \
            {                                                                       \
                h16x2 c0_ = __builtin_amdgcn_cvt_pkrtz(xfa[0], xfa[1]);             \
                h16x2 c1_ = __builtin_amdgcn_cvt_pkrtz(xfa[2], xfa[3]);             \
                h16x2 c2_ = __builtin_amdgcn_cvt_pkrtz(xfb[0], xfb[1]);             \
                h16x2 c3_ = __builtin_amdgcn_cvt_pkrtz(xfb[2], xfb[3]);             \
                xcur[0] = (_Float16)c0_[0]; xcur[1] = (_Float16)c0_[1];             \
                xcur[2] = (_Float16)c1_[0]; xcur[3] = (_Float16)c1_[1];             \
                xcur[4] = (_Float16)c2_[0]; xcur[5] = (_Float16)c2_[1];             \
                xcur[6] = (_Float16)c3_[0]; xcur[7] = (_Float16)c3_[1];             \
            }                                                                       \
            if (DO_XL) {                                                            \
                xfa = *reinterpret_cast<const f32x4*>(xp + (size_t)(XI) * FIN);     \
                xfb = *reinterpret_cast<const f32x4*>(xp + (size_t)(XI) * FIN + 4); \
            }                                                                       \
            if (DO_A) {                                                             \
                f32x4 a0 = bias0, a1 = bias1;                                       \
                /* register-only x-MFMAs first: fill the post-barrier LDS stall */  \
                a0 = MFMA(wf[0], xcur, a0, 0, 0, 0);                                \
                a1 = MFMA(wf[3], xcur, a1, 0, 0, 0);                                \
                f16x8 rh0a = *reinterpret_cast<const f16x8*>(&H0[(P) ^ 1][lm][q8]);      \
                f16x8 rh0b = *reinterpret_cast<const f16x8*>(&H0[(P) ^ 1][lm][32 + q8]); \
                a0 = MFMA(wf[1], rh0a, a0, 0, 0, 0);                                \
                a1 = MFMA(wf[4], rh0a, a1, 0, 0, 0);                                \
                a0 = MFMA(wf[2], rh0b, a0, 0, 0, 0);                                \
                a1 = MFMA(wf[5], rh0b, a1, 0, 0, 0);                                \
                float hv0 = lstm_cell(a0, c0a);                                     \
                float hv1 = lstm_cell(a1, c0b);                                     \
                H0[P][lm][d0] = (_Float16)hv0;                                      \
                H0[P][lm][d1] = (_Float16)hv1;                                      \
            }                                                                       \
        } else if (DO_B) {                                                          \
            /* split reads: H0 pair -> 4 MFMA -> H1 pair -> 4 MFMA */               \
            f16x8 rh0a = *reinterpret_cast<const f16x8*>(&H0[(P) ^ 1][lm][q8]);      \
            f16x8 rh0b = *reinterpret_cast<const f16x8*>(&H0[(P) ^ 1][lm][32 + q8]); \
            f32x4 a0 = bias0, a1 = bias1;                                           \
            a0 = MFMA(wf[0], rh0a, a0, 0, 0, 0);                                    \
            a1 = MFMA(wf[4], rh0a, a1, 0, 0, 0);                                    \
            a0 = MFMA(wf[1], rh0b, a0, 0, 0, 0);                                    \
            a1 = MFMA(wf[5], rh0b, a1, 0, 0, 0);                                    \
            f16x8 rh1a = *reinterpret_cast<const f16x8*>(&H1[P][lm][q8]);            \
            f16x8 rh1b = *reinterpret_cast<const f16x8*>(&H1[P][lm][32 + q8]);       \
            a0 = MFMA(wf[2], rh1a, a0, 0, 0, 0);                                    \
            a1 = MFMA(wf[6], rh1a, a1, 0, 0, 0);                                    \
            a0 = MFMA(wf[3], rh1b, a0, 0, 0, 0);                                    \
            a1 = MFMA(wf[7], rh1b, a1, 0, 0, 0);                                    \
            float hv0 = lstm_cell(a0, c1a);                                         \
            float hv1 = lstm_cell(a1, c1b);                                         \
            H1[(P) ^ 1][lm][d0] = (_Float16)hv0;                                    \
            H1[(P) ^ 1][lm][d1] = (_Float16)hv1;                                    \
            lastB0 = hv0; lastB1 = hv1;                                             \
        }                                                                           \
        BAR_LDS();                                                                  \
    }

    // peel i = 0 (P=0): A only; prefetch x(1)
    INTERVAL(0, true, false, true, 1)

    // main: i = 1..254 as 127 (odd,even) pairs, fully active.
    // prefetch index i+1 never exceeds 255 (ii=126 -> loads x(254), x(255)).
    #pragma unroll 1
    for (int ii = 0; ii < 127; ++ii) {
        const int i1 = 2 * ii + 1;
        INTERVAL(1, true, true, true, i1 + 1)
        INTERVAL(0, true, true, true, i1 + 2)
    }

    // peel i = 255 (P=1): A+B, no prefetch (consumes x(255))
    INTERVAL(1, true, true, false, 0)
    // peel i = 256 (P=0): B only -> h1(255)
    INTERVAL(0, false, true, false, 0)

#undef INTERVAL
#undef MFMA

    if (!isA) {
        HF[lm][d0] = lastB0;
        HF[lm][d1] = lastB1;
    }
    __syncthreads();

    // ================= Head: LayerNorm + MLP (wave w -> batch row w) =========
    const float lngv = ln_g[lane], lnbv = ln_b[lane];
    const float b1v = b1[lane], w2v = w2[lane];
    const float* w1row = w1 + lane * 64;
    {
        float v  = HF[wave][lane];
        float mu = wsum(v) * (1.0f / 64.0f);
        float dv = v - mu;
        float var = wsum(dv * dv) * (1.0f / 64.0f);
        float ln = dv * rsqrtf(var + 1e-5f) * lngv + lnbv;
        LNB[wave][lane] = ln;   // wave-private buffer
        float s = b1v;
        #pragma unroll
        for (int dd = 0; dd < 64; ++dd)
            s = fmaf(LNB[wave][dd], w1row[dd], s);
        s = fmaxf(s, 0.0f);
        float y = wsum(s * w2v);
        if (lane == 0) out[b0 + wave] = y + b2[0];
    }
}

extern "C" void kernel_launch(void* const* d_in, const int* in_sizes, int n_in,
                              void* d_out, int out_size, void* d_ws, size_t ws_size,
                              hipStream_t stream) {
    const float* x     = (const float*)d_in[0];
    const float* w_ih0 = (const float*)d_in[1];
    const float* w_hh0 = (const float*)d_in[2];
    const float* b_ih0 = (const float*)d_in[3];
    const float* b_hh0 = (const float*)d_in[4];
    const float* w_ih1 = (const float*)d_in[5];
    const float* w_hh1 = (const float*)d_in[6];
    const float* b_ih1 = (const float*)d_in[7];
    const float* b_hh1 = (const float*)d_in[8];
    const float* ln_g  = (const float*)d_in[9];
    const float* ln_b  = (const float*)d_in[10];
    const float* w1    = (const float*)d_in[11];
    const float* b1    = (const float*)d_in[12];
    const float* w2    = (const float*)d_in[13];
    const float* b2    = (const float*)d_in[14];
    lstm_fused<<<dim3(256), dim3(1024), 0, stream>>>(
        x, w_ih0, w_hh0, b_ih0, b_hh0,
        w_ih1, w_hh1, b_ih1, b_hh1,
        ln_g, ln_b, w1, b1, w2, b2, (float*)d_out);
}

// Round 9
// 361.852 us; speedup vs baseline: 1.0098x; 1.0098x over previous
//
#include <hip/hip_runtime.h>

#define TSEQ 256
#define FIN  32
#define HID  64

#define LOG2E    1.4426950408889634f
#define TWOLOG2E 2.8853900817779268f

typedef _Float16 f16x8 __attribute__((ext_vector_type(8)));
typedef __fp16   h16x2 __attribute__((ext_vector_type(2)));   // cvt_pkrtz return type
typedef float    f32x4 __attribute__((ext_vector_type(4)));

// Raw v_exp_f32 (flush-to-zero below 2^-126). FTZ is the mathematically
// correct limit for sigmoid/tanh decode. __builtin_exp2f lowers to OCML's
// IEEE exp2f with a subnormal fixup (~8 VALU/call) -- R8's regression.
#if __has_builtin(__builtin_amdgcn_exp2f)
__device__ __forceinline__ float fast_exp2(float x) { return __builtin_amdgcn_exp2f(x); }
#else
extern "C" __device__ float __ocml_native_exp2_f32(float);
__device__ __forceinline__ float fast_exp2(float x) { return __ocml_native_exp2_f32(x); }
#endif

// Barrier with LDS-only drain: __syncthreads() forces vmcnt(0) too, which
// would couple the x global-load prefetch into every barrier.
#define BAR_LDS() do { asm volatile("s_waitcnt lgkmcnt(0)" ::: "memory"); \
                       __builtin_amdgcn_s_barrier(); } while (0)

__device__ __forceinline__ float wsum(float v) {
    #pragma unroll
    for (int off = 32; off > 0; off >>= 1) v += __shfl_xor(v, off, 64);
    return v;
}

// Gates arrive PRE-SCALED (log2e folded into weights/biases):
//   g0 = -log2e*i, g1 = -log2e*f, g2 = 2log2e*g, g3 = -log2e*o
// Merged-denominator decode: one rcp serves sigma(f) AND sigma(i)*tanh(g).
// Trans ops/cell: 5 exp + 2 rcp. c clamped +-15 via med3.
__device__ __forceinline__ float lstm_cell(const f32x4 g, float& c) {
    float ei = fast_exp2(g[0]);
    float ef = fast_exp2(g[1]);
    float yg = fast_exp2(g[2]);
    float eo = fast_exp2(g[3]);
    float t1 = 1.0f + ei;
    float t2 = 1.0f + ef;
    float p  = t1 * (yg + 1.0f);
    float r  = __builtin_amdgcn_rcpf(p * t2);
    float ig = (yg - 1.0f) * t2 * r;   // sigma(i)*tanh(g)
    float sf = p * r;                  // sigma(f)
    c = fmaf(sf, c, ig);
    float cc = __builtin_amdgcn_fmed3f(c, -15.0f, 15.0f);
    float yc = fast_exp2(TWOLOG2E * cc);
    return (yc - 1.0f) * __builtin_amdgcn_rcpf((1.0f + eo) * (yc + 1.0f));
}

// R12: 8 waves x 4 gate-tiles (was 16 x 2). Same 16-batch block, same
// per-SIMD VALU issue (2 waves x 28 trans = 4 x 14), but:
//  - LDS b128 reads/CU-interval 48 -> 24 (B-fragments shared across 4 tiles)
//  - barrier domain 16 -> 8 waves; 2x in-wave ILP (4 indep acc/cell chains)
//  - x-convert redundancy halved (4 A-waves)
//   waves 0-3 (A): layer-0 tiles T = 4w..4w+3;  waves 4-7 (B): layer-1 ditto.
// Skew pipeline unchanged: interval i = layer0 step i + layer1 step i-1,
// one BAR_LDS per interval.
__global__ __launch_bounds__(512, 2)
void lstm_fused(const float* __restrict__ x,
                const float* __restrict__ w_ih0, const float* __restrict__ w_hh0,
                const float* __restrict__ b_ih0, const float* __restrict__ b_hh0,
                const float* __restrict__ w_ih1, const float* __restrict__ w_hh1,
                const float* __restrict__ b_ih1, const float* __restrict__ b_hh1,
                const float* __restrict__ ln_g, const float* __restrict__ ln_b,
                const float* __restrict__ w1, const float* __restrict__ b1,
                const float* __restrict__ w2, const float* __restrict__ b2,
                float* __restrict__ out)
{
    __shared__ __align__(16) _Float16 H0[2][16][72];  // h0 parity buffers
    __shared__ __align__(16) _Float16 H1[2][16][72];  // h1 parity buffers
    __shared__ __align__(16) float HF[16][68];        // final h1 (fp32) for head
    __shared__ __align__(16) float LNB[16][64];       // per-row layernorm buffer

    const int tid  = threadIdx.x;
    const int wave = tid >> 6;        // 0..7
    const int lane = tid & 63;
    const int q    = lane >> 4;
    const int lm   = lane & 15;
    const int q8   = q * 8;
    const int b0   = blockIdx.x * 16;

    const bool isA = wave < 4;
    const int  wt  = wave & 3;
    // tile t (0..3) -> T = wt*4+t; np = T*16+lm; row = (np&3)*64+(np>>2);
    // d = T*4+q. rbase collects the lm-dependent part.
    const int rbase = (lm & 3) * 64 + (lm >> 2);
    const int dq0   = wt * 16 + q;            // d for tile 0; +4 per tile
    // log2e folding: weight row's gate type = lm&3 (g rows get +2log2e)
    const float wsc = ((lm & 3) == 2) ? TWOLOG2E : -LOG2E;

    // wf: A uses [t*3+k], k={x,h0a,h0b}; B uses [t*4+k], k={ia,ib,ha,hb}
    f16x8 wf[16];
    f32x4 biasv[4];
    if (isA) {
        #pragma unroll
        for (int t = 0; t < 4; ++t) {
            const int row = rbase + wt * 16 + t * 4;
            const float* p0 = w_ih0 + row * FIN + q8;
            const float* p1 = w_hh0 + row * HID + q8;
            const float* p2 = p1 + 32;
            #pragma unroll
            for (int j = 0; j < 8; ++j) {
                wf[t * 3 + 0][j] = (_Float16)(wsc * p0[j]);
                wf[t * 3 + 1][j] = (_Float16)(wsc * p1[j]);
                wf[t * 3 + 2][j] = (_Float16)(wsc * p2[j]);
            }
            const int d = dq0 + t * 4;
            #pragma unroll
            for (int r = 0; r < 4; ++r) {
                const float s = (r == 2) ? TWOLOG2E : -LOG2E;
                biasv[t][r] = s * (b_ih0[r * 64 + d] + b_hh0[r * 64 + d]);
            }
        }
    } else {
        #pragma unroll
        for (int t = 0; t < 4; ++t) {
            const int row = rbase + wt * 16 + t * 4;
            const float* p0 = w_ih1 + row * HID + q8;
            const float* p1 = p0 + 32;
            const float* p2 = w_hh1 + row * HID + q8;
            const float* p3 = p2 + 32;
            #pragma unroll
            for (int j = 0; j < 8; ++j) {
                wf[t * 4 + 0][j] = (_Float16)(wsc * p0[j]);
                wf[t * 4 + 1][j] = (_Float16)(wsc * p1[j]);
                wf[t * 4 + 2][j] = (_Float16)(wsc * p2[j]);
                wf[t * 4 + 3][j] = (_Float16)(wsc * p3[j]);
            }
            const int d = dq0 + t * 4;
            #pragma unroll
            for (int r = 0; r < 4; ++r) {
                const float s = (r == 2) ? TWOLOG2E : -LOG2E;
                biasv[t][r] = s * (b_ih1[r * 64 + d] + b_hh1[r * 64 + d]);
            }
        }
    }

    // x prefetch registers: xfa/xfb hold x(i) in f32 at interval-i entry
    const float* xp = x + (size_t)(b0 + lm) * TSEQ * FIN + q8;
    f32x4 xfa, xfb;
    if (isA) {
        xfa = *reinterpret_cast<const f32x4*>(xp);
        xfb = *reinterpret_cast<const f32x4*>(xp + 4);
    }

    // zero h state (both parities)
    for (int i = tid; i < 2 * 16 * 72; i += 512) {
        ((_Float16*)H0)[i] = (_Float16)0.0f;
        ((_Float16*)H1)[i] = (_Float16)0.0f;
    }
    float cs0 = 0.0f, cs1 = 0.0f, cs2 = 0.0f, cs3 = 0.0f;   // cell state x4
    float lastB0 = 0.0f, lastB1 = 0.0f, lastB2 = 0.0f, lastB3 = 0.0f;
    __syncthreads();

#define MFMA __builtin_amdgcn_mfma_f32_16x16x32_f16
// Interval i (parity P=i&1): A-waves compute h0(i) for their 4 tiles,
// reading H0[P^1], writing H0[P]; B-waves compute h1(i-1), reading H0[P^1]
// and H1[P], writing H1[P^1]. x: convert prefetched x(i), load x(XI=i+1).
#define INTERVAL(P, DO_A, DO_B, DO_XL, XI)                                          \
    {                                                                               \
        if (isA) {                                                                  \
            f16x8 xcur;                                                             \
            {                                                                       \
                h16x2 c0_ = __builtin_amdgcn_cvt_pkrtz(xfa[0], xfa[1]);             \
                h16x2 c1_ = __builtin_amdgcn_cvt_pkrtz(xfa[2], xfa[3]);             \
                h16x2 c2_ = __builtin_amdgcn_cvt_pkrtz(xfb[0], xfb[1]);             \
                h16x2 c3_ = __builtin_amdgcn_cvt_pkrtz(xfb[2], xfb[3]);             \
                xcur[0] = (_Float16)c0_[0]; xcur[1] = (_Float16)c0_[1];             \
                xcur[2] = (_Float16)c1_[0]; xcur[3] = (_Float16)c1_[1];             \
                xcur[4] = (_Float16)c2_[0]; xcur[5] = (_Float16)c2_[1];             \
                xcur[6] = (_Float16)c3_[0]; xcur[7] = (_Float16)c3_[1];             \
            }                                                                       \
            if (DO_XL) {                                                            \
                xfa = *reinterpret_cast<const f32x4*>(xp + (size_t)(XI) * FIN);     \
                xfb = *reinterpret_cast<const f32x4*>(xp + (size_t)(XI) * FIN + 4); \
            }                                                                       \
            if (DO_A) {                                                             \
                f32x4 a0 = biasv[0], a1 = biasv[1], a2 = biasv[2], a3 = biasv[3];   \
                /* register-only x-MFMAs first (fill post-barrier LDS latency) */   \
                a0 = MFMA(wf[0], xcur, a0, 0, 0, 0);                                \
                a1 = MFMA(wf[3], xcur, a1, 0, 0, 0);                                \
                a2 = MFMA(wf[6], xcur, a2, 0, 0, 0);                                \
                a3 = MFMA(wf[9], xcur, a3, 0, 0, 0);                                \
                f16x8 rh0a = *reinterpret_cast<const f16x8*>(&H0[(P) ^ 1][lm][q8]);      \
                f16x8 rh0b = *reinterpret_cast<const f16x8*>(&H0[(P) ^ 1][lm][32 + q8]); \
                a0 = MFMA(wf[1],  rh0a, a0, 0, 0, 0);                               \
                a1 = MFMA(wf[4],  rh0a, a1, 0, 0, 0);                               \
                a2 = MFMA(wf[7],  rh0a, a2, 0, 0, 0);                               \
                a3 = MFMA(wf[10], rh0a, a3, 0, 0, 0);                               \
                a0 = MFMA(wf[2],  rh0b, a0, 0, 0, 0);                               \
                a1 = MFMA(wf[5],  rh0b, a1, 0, 0, 0);                               \
                a2 = MFMA(wf[8],  rh0b, a2, 0, 0, 0);                               \
                a3 = MFMA(wf[11], rh0b, a3, 0, 0, 0);                               \
                float hv0 = lstm_cell(a0, cs0);                                     \
                float hv1 = lstm_cell(a1, cs1);                                     \
                float hv2 = lstm_cell(a2, cs2);                                     \
                float hv3 = lstm_cell(a3, cs3);                                     \
                H0[P][lm][dq0]      = (_Float16)hv0;                                \
                H0[P][lm][dq0 + 4]  = (_Float16)hv1;                                \
                H0[P][lm][dq0 + 8]  = (_Float16)hv2;                                \
                H0[P][lm][dq0 + 12] = (_Float16)hv3;                                \
            }                                                                       \
        } else if (DO_B) {                                                          \
            f16x8 rh0a = *reinterpret_cast<const f16x8*>(&H0[(P) ^ 1][lm][q8]);      \
            f16x8 rh0b = *reinterpret_cast<const f16x8*>(&H0[(P) ^ 1][lm][32 + q8]); \
            f32x4 a0 = biasv[0], a1 = biasv[1], a2 = biasv[2], a3 = biasv[3];       \
            a0 = MFMA(wf[0],  rh0a, a0, 0, 0, 0);                                   \
            a1 = MFMA(wf[4],  rh0a, a1, 0, 0, 0);                                   \
            a2 = MFMA(wf[8],  rh0a, a2, 0, 0, 0);                                   \
            a3 = MFMA(wf[12], rh0a, a3, 0, 0, 0);                                   \
            a0 = MFMA(wf[1],  rh0b, a0, 0, 0, 0);                                   \
            a1 = MFMA(wf[5],  rh0b, a1, 0, 0, 0);                                   \
            a2 = MFMA(wf[9],  rh0b, a2, 0, 0, 0);                                   \
            a3 = MFMA(wf[13], rh0b, a3, 0, 0, 0);                                   \
            f16x8 rh1a = *reinterpret_cast<const f16x8*>(&H1[P][lm][q8]);            \
            f16x8 rh1b = *reinterpret_cast<const f16x8*>(&H1[P][lm][32 + q8]);       \
            a0 = MFMA(wf[2],  rh1a, a0, 0, 0, 0);                                   \
            a1 = MFMA(wf[6],  rh1a, a1, 0, 0, 0);                                   \
            a2 = MFMA(wf[10], rh1a, a2, 0, 0, 0);                                   \
            a3 = MFMA(wf[14], rh1a, a3, 0, 0, 0);                                   \
            a0 = MFMA(wf[3],  rh1b, a0, 0, 0, 0);                                   \
            a1 = MFMA(wf[7],  rh1b, a1, 0, 0, 0);                                   \
            a2 = MFMA(wf[11], rh1b, a2, 0, 0, 0);                                   \
            a3 = MFMA(wf[15], rh1b, a3, 0, 0, 0);                                   \
            float hv0 = lstm_cell(a0, cs0);                                         \
            float hv1 = lstm_cell(a1, cs1);                                         \
            float hv2 = lstm_cell(a2, cs2);                                         \
            float hv3 = lstm_cell(a3, cs3);                                         \
            H1[(P) ^ 1][lm][dq0]      = (_Float16)hv0;                              \
            H1[(P) ^ 1][lm][dq0 + 4]  = (_Float16)hv1;                              \
            H1[(P) ^ 1][lm][dq0 + 8]  = (_Float16)hv2;                              \
            H1[(P) ^ 1][lm][dq0 + 12] = (_Float16)hv3;                              \
            lastB0 = hv0; lastB1 = hv1; lastB2 = hv2; lastB3 = hv3;                 \
        }                                                                           \
        BAR_LDS();                                                                  \
    }

    // peel i = 0 (P=0): A only; prefetch x(1)
    INTERVAL(0, true, false, true, 1)

    // main: i = 1..254 as 127 (odd,even) pairs, fully active.
    // prefetch index i+1 never exceeds 255 (ii=126 -> loads x(254), x(255)).
    #pragma unroll 1
    for (int ii = 0; ii < 127; ++ii) {
        const int i1 = 2 * ii + 1;
        INTERVAL(1, true, true, true, i1 + 1)
        INTERVAL(0, true, true, true, i1 + 2)
    }

    // peel i = 255 (P=1): A+B, no prefetch (consumes x(255))
    INTERVAL(1, true, true, false, 0)
    // peel i = 256 (P=0): B only -> h1(255)
    INTERVAL(0, false, true, false, 0)

#undef INTERVAL
#undef MFMA

    if (!isA) {
        HF[lm][dq0]      = lastB0;
        HF[lm][dq0 + 4]  = lastB1;
        HF[lm][dq0 + 8]  = lastB2;
        HF[lm][dq0 + 12] = lastB3;
    }
    __syncthreads();

    // ============ Head: LayerNorm + MLP (wave w -> rows w, w+8) ============
    const float lngv = ln_g[lane], lnbv = ln_b[lane];
    const float b1v = b1[lane], w2v = w2[lane];
    const float* w1row = w1 + lane * 64;
    #pragma unroll
    for (int rr = wave; rr < 16; rr += 8) {
        float v  = HF[rr][lane];
        float mu = wsum(v) * (1.0f / 64.0f);
        float dv = v - mu;
        float var = wsum(dv * dv) * (1.0f / 64.0f);
        float ln = dv * rsqrtf(var + 1e-5f) * lngv + lnbv;
        LNB[rr][lane] = ln;
        float s = b1v;
        #pragma unroll
        for (int dd = 0; dd < 64; ++dd)
            s = fmaf(LNB[rr][dd], w1row[dd], s);
        s = fmaxf(s, 0.0f);
        float y = wsum(s * w2v);
        if (lane == 0) out[b0 + rr] = y + b2[0];
    }
}

extern "C" void kernel_launch(void* const* d_in, const int* in_sizes, int n_in,
                              void* d_out, int out_size, void* d_ws, size_t ws_size,
                              hipStream_t stream) {
    const float* x     = (const float*)d_in[0];
    const float* w_ih0 = (const float*)d_in[1];
    const float* w_hh0 = (const float*)d_in[2];
    const float* b_ih0 = (const float*)d_in[3];
    const float* b_hh0 = (const float*)d_in[4];
    const float* w_ih1 = (const float*)d_in[5];
    const float* w_hh1 = (const float*)d_in[6];
    const float* b_ih1 = (const float*)d_in[7];
    const float* b_hh1 = (const float*)d_in[8];
    const float* ln_g  = (const float*)d_in[9];
    const float* ln_b  = (const float*)d_in[10];
    const float* w1    = (const float*)d_in[11];
    const float* b1    = (const float*)d_in[12];
    const float* w2    = (const float*)d_in[13];
    const float* b2    = (const float*)d_in[14];
    lstm_fused<<<dim3(256), dim3(512), 0, stream>>>(
        x, w_ih0, w_hh0, b_ih0, b_hh0,
        w_ih1, w_hh1, b_ih1, b_hh1,
        ln_g, ln_b, w1, b1, w2, b2, (float*)d_out);
}